// Round 3
// baseline (1325.304 us; speedup 1.0000x reference)
//
#include <hip/hip_runtime.h>

typedef unsigned short u16;
typedef short s16x8 __attribute__((ext_vector_type(8)));
typedef u16 u16x4 __attribute__((ext_vector_type(4)));
typedef float f32x4 __attribute__((ext_vector_type(4)));

#define T_N   1024
#define NEGV  -1e6f
#define MB    (1L << 20)

__device__ __forceinline__ u16 f2bf(float f) {
    unsigned u = __float_as_uint(f);
    u += 0x7fffu + ((u >> 16) & 1u);     // RNE
    return (u16)(u >> 16);
}
__device__ __forceinline__ float bf2f(u16 h) {
    return __uint_as_float(((unsigned)h) << 16);
}
__device__ __forceinline__ f32x4 mfma16(s16x8 a, s16x8 b, f32x4 c) {
    return __builtin_amdgcn_mfma_f32_16x16x32_bf16(a, b, c, 0, 0, 0);
}
// async global->LDS, 16B per lane; LDS dest = wave-uniform base + lane*16 (m97/m104)
__device__ __forceinline__ void gll16(const u16* g, u16* l) {
    __builtin_amdgcn_global_load_lds((const __attribute__((address_space(1))) void*)g,
                                     (__attribute__((address_space(3))) void*)l, 16, 0, 0);
}

// ---------------------------------------------------------------- transpose+cast
struct P6 { const float* s[6]; u16* d[6]; };

__global__ __launch_bounds__(256) void transpose_cast_batch(P6 pp, int K, int N) {
    const float* __restrict__ src = pp.s[blockIdx.z];
    u16* __restrict__ dst = pp.d[blockIdx.z];
    __shared__ float tile[32][33];
    int nb = blockIdx.x * 32, kb = blockIdx.y * 32;
    int tx = threadIdx.x & 31, ty = threadIdx.x >> 5;   // ty 0..7
    #pragma unroll
    for (int i = 0; i < 4; i++)
        tile[ty + 8*i][tx] = src[(long)(kb + ty + 8*i) * N + nb + tx];
    __syncthreads();
    #pragma unroll
    for (int i = 0; i < 4; i++)
        dst[(long)(nb + ty + 8*i) * K + kb + tx] = f2bf(tile[tx][ty + 8*i]);
}

__global__ __launch_bounds__(256) void cast_bf16_kernel(const float* __restrict__ src,
                                                        u16* __restrict__ dst, long n) {
    long i = ((long)blockIdx.x * 256 + threadIdx.x) * 4;
    if (i >= n) return;
    float4 v = *(const float4*)(src + i);
    u16x4 o = { f2bf(v.x), f2bf(v.y), f2bf(v.z), f2bf(v.w) };
    *(u16x4*)(dst + i) = o;
}

// ---------------------------------------------------------------- GEMM: C[M,N] = A[M,K] * Bt[N,K]^T
// m97-style: global_load_lds width-16 staging into chunk-major LDS
// (slot byte = kchunk*2048 + row*16) -> conflict-free ds_read_b128 fragments.
// 128x128 tile, BK=32, 4 waves x 4x4 of 16x16x32 mfma. lda/ldb/ldc in elements.
template<typename OutT, bool RELU, bool HAS_BIAS>
__global__ __launch_bounds__(256) void gemm_bt(
    const u16* __restrict__ A, const u16* __restrict__ Bt, OutT* __restrict__ C,
    const float* __restrict__ bias, int M, int N, int K,
    int lda, int ldb, int ldc,
    int batchDivA, long sA, long sB, long sC)
{
    A  += (long)(blockIdx.z / batchDivA) * sA;
    Bt += (long)blockIdx.z * sB;
    C  += (long)blockIdx.z * sC;
    __shared__ __align__(16) u16 As[4096];   // 8 KB, [chunk 0..3][row 0..127] x 8 elems
    __shared__ __align__(16) u16 Bs[4096];
    const int tid = threadIdx.x;
    const int wave = tid >> 6, lane = tid & 63;
    const int quad = lane >> 4, l16 = lane & 15;
    const int wr = (wave >> 1) * 64, wc = (wave & 1) * 64;
    const long row0 = (long)blockIdx.y * 128, col0 = (long)blockIdx.x * 128;

    f32x4 acc[4][4] = {};

    // wave w stages k-chunk w (elements w*8..w*8+7) for rows lane and 64+lane
    const u16* Ap0 = A + (row0 + lane) * (long)lda + wave * 8;
    const u16* Ap1 = Ap0 + 64L * lda;
    const u16* Bp0 = Bt + (col0 + lane) * (long)ldb + wave * 8;
    const u16* Bp1 = Bp0 + 64L * ldb;
    u16* AsW0 = &As[wave * 1024];
    u16* AsW1 = &As[wave * 1024 + 512];
    u16* BsW0 = &Bs[wave * 1024];
    u16* BsW1 = &Bs[wave * 1024 + 512];
    const bool aok0 = (row0 + lane) < M;
    const bool aok1 = (row0 + 64 + lane) < M;

    for (int k0 = 0; k0 < K; k0 += 32) {
        __syncthreads();                       // prev-iter LDS reads done
        if (aok0) gll16(Ap0 + k0, AsW0);
        if (aok1) gll16(Ap1 + k0, AsW1);
        gll16(Bp0 + k0, BsW0);
        gll16(Bp1 + k0, BsW1);
        __syncthreads();                       // compiler drains vmcnt before barrier
        s16x8 af[4], bfr[4];
        #pragma unroll
        for (int i = 0; i < 4; i++)
            af[i]  = *(const s16x8*)&As[quad * 1024 + (wr + i*16 + l16) * 8];
        #pragma unroll
        for (int j = 0; j < 4; j++)
            bfr[j] = *(const s16x8*)&Bs[quad * 1024 + (wc + j*16 + l16) * 8];
        #pragma unroll
        for (int i = 0; i < 4; i++)
            #pragma unroll
            for (int j = 0; j < 4; j++)
                acc[i][j] = mfma16(af[i], bfr[j], acc[i][j]);
    }

    #pragma unroll
    for (int i = 0; i < 4; i++) {
        long row = row0 + wr + i*16 + quad*4;
        #pragma unroll
        for (int j = 0; j < 4; j++) {
            long col = col0 + wc + j*16 + l16;
            float bv = 0.f;
            if constexpr (HAS_BIAS) bv = bias[col];
            #pragma unroll
            for (int r = 0; r < 4; r++) {
                if (row + r < M) {
                    float v = acc[i][j][r] + bv;
                    if constexpr (RELU) v = fmaxf(v, 0.f);
                    if constexpr (sizeof(OutT) == 2) C[(row + r) * (long)ldc + col] = f2bf(v);
                    else                             C[(row + r) * (long)ldc + col] = v;
                }
            }
        }
    }
}

// ---------------------------------------------------------------- flash attention (dh=64, H=16)
// strides (elements) for Q/K/V rows; O stride fixed 1024.
template<bool CAUSAL>
__global__ __launch_bounds__(256) void flash_attn_kernel(
    const u16* __restrict__ Q, const u16* __restrict__ Kg, const u16* __restrict__ Vg,
    const int* __restrict__ valid_len, u16* __restrict__ O,
    int qld, int kld, int vld)
{
    const int h = blockIdx.y, b = blockIdx.z;
    const int qt0 = blockIdx.x * 64;
    const int tid = threadIdx.x;
    const int wave = tid >> 6, lane = tid & 63;
    const int quad = lane >> 4, l16 = lane & 15;

    __shared__ __align__(16) u16 Qs[64][72];
    __shared__ __align__(16) u16 Ks[64][72];
    __shared__ __align__(16) u16 Vt[64][72];
    __shared__ __align__(16) u16 Ps[4][16][72];

    const int sr = tid >> 2, scc = (tid & 3) * 16;
    {
        const u16* qp = Q + ((long)b * T_N + qt0 + sr) * qld + h * 64 + scc;
        *(s16x8*)&Qs[sr][scc]     = *(const s16x8*)qp;
        *(s16x8*)&Qs[sr][scc + 8] = *(const s16x8*)(qp + 8);
    }
    float m_i[4] = {-1e30f, -1e30f, -1e30f, -1e30f};
    float l_i[4] = {0.f, 0.f, 0.f, 0.f};
    f32x4 o_acc[4] = {};

    int vl = 0, kend;
    if (CAUSAL) kend = qt0 + 64;
    else { vl = valid_len[b]; kend = (vl + 63) & ~63; }

    for (int kv0 = 0; kv0 < kend; kv0 += 64) {
        __syncthreads();
        {
            const u16* kp = Kg + ((long)b * T_N + kv0 + sr) * kld + h * 64 + scc;
            *(s16x8*)&Ks[sr][scc]     = *(const s16x8*)kp;
            *(s16x8*)&Ks[sr][scc + 8] = *(const s16x8*)(kp + 8);
            const u16* vp = Vg + ((long)b * T_N + kv0 + sr) * vld + h * 64 + scc;
            s16x8 v0 = *(const s16x8*)vp;
            s16x8 v1 = *(const s16x8*)(vp + 8);
            #pragma unroll
            for (int j = 0; j < 8; j++) {
                Vt[scc + j][sr]     = (u16)v0[j];
                Vt[scc + 8 + j][sr] = (u16)v1[j];
            }
        }
        __syncthreads();
        f32x4 sc[4] = {};
        #pragma unroll
        for (int kk = 0; kk < 64; kk += 32) {
            s16x8 aq = *(const s16x8*)&Qs[wave*16 + l16][kk + quad*8];
            #pragma unroll
            for (int j = 0; j < 4; j++) {
                s16x8 bk = *(const s16x8*)&Ks[j*16 + l16][kk + quad*8];
                sc[j] = mfma16(aq, bk, sc[j]);
            }
        }
        const int qrow = qt0 + wave*16 + quad*4;
        #pragma unroll
        for (int j = 0; j < 4; j++) {
            int kcol = kv0 + j*16 + l16;
            #pragma unroll
            for (int r = 0; r < 4; r++) {
                float s = sc[j][r] * 0.125f;
                bool ok = CAUSAL ? (kcol <= qrow + r) : (kcol < vl);
                sc[j][r] = ok ? s : -1e30f;
            }
        }
        float alpha[4];
        #pragma unroll
        for (int r = 0; r < 4; r++) {
            float mx = fmaxf(fmaxf(sc[0][r], sc[1][r]), fmaxf(sc[2][r], sc[3][r]));
            #pragma unroll
            for (int d = 1; d < 16; d <<= 1) mx = fmaxf(mx, __shfl_xor(mx, d, 64));
            float mn = fmaxf(m_i[r], mx);
            alpha[r] = __expf(m_i[r] - mn);
            m_i[r] = mn;
        }
        float rsum[4] = {0.f, 0.f, 0.f, 0.f};
        #pragma unroll
        for (int j = 0; j < 4; j++)
            #pragma unroll
            for (int r = 0; r < 4; r++) {
                float pv = __expf(sc[j][r] - m_i[r]);
                sc[j][r] = pv;
                rsum[r] += pv;
            }
        #pragma unroll
        for (int r = 0; r < 4; r++) {
            #pragma unroll
            for (int d = 1; d < 16; d <<= 1) rsum[r] += __shfl_xor(rsum[r], d, 64);
            l_i[r] = l_i[r] * alpha[r] + rsum[r];
        }
        #pragma unroll
        for (int j = 0; j < 4; j++)
            #pragma unroll
            for (int r = 0; r < 4; r++)
                Ps[wave][quad*4 + r][j*16 + l16] = f2bf(sc[j][r]);
        #pragma unroll
        for (int j2 = 0; j2 < 4; j2++)
            #pragma unroll
            for (int r = 0; r < 4; r++)
                o_acc[j2][r] *= alpha[r];
        __syncthreads();
        #pragma unroll
        for (int kk = 0; kk < 64; kk += 32) {
            s16x8 ap = *(const s16x8*)&Ps[wave][l16][kk + quad*8];
            #pragma unroll
            for (int j2 = 0; j2 < 4; j2++) {
                s16x8 bv = *(const s16x8*)&Vt[j2*16 + l16][kk + quad*8];
                o_acc[j2] = mfma16(ap, bv, o_acc[j2]);
            }
        }
    }
    #pragma unroll
    for (int j2 = 0; j2 < 4; j2++) {
        #pragma unroll
        for (int r = 0; r < 4; r++) {
            float v = o_acc[j2][r] / l_i[r];
            long row = (long)b * T_N + qt0 + wave*16 + quad*4 + r;
            O[row * 1024 + h*64 + j2*16 + l16] = f2bf(v);
        }
    }
}

// ---------------------------------------------------------------- ssc[b,t,s] = qs.ks/32 (masked)
__global__ __launch_bounds__(256) void ssc_kernel(
    const u16* __restrict__ qs, const u16* __restrict__ ks,
    const int* __restrict__ svl, float* __restrict__ ssc, int qld)
{
    const int t = blockIdx.x, b = blockIdx.y;
    const int wave = threadIdx.x >> 6, lane = threadIdx.x & 63;
    const u16* qrow = qs + ((long)b * T_N + t) * qld + lane * 16;
    const int vl = svl[b];
    for (int s = wave; s < 16; s += 4) {
        const u16* krow = ks + ((long)b * 16 + s) * 1024 + lane * 16;
        float acc = 0.f;
        #pragma unroll
        for (int seg = 0; seg < 2; seg++) {
            s16x8 qv = *(const s16x8*)(qrow + seg*8);
            s16x8 kv = *(const s16x8*)(krow + seg*8);
            #pragma unroll
            for (int j = 0; j < 8; j++) acc += bf2f((u16)qv[j]) * bf2f((u16)kv[j]);
        }
        #pragma unroll
        for (int d = 1; d < 64; d <<= 1) acc += __shfl_xor(acc, d, 64);
        if (lane == 0)
            ssc[((long)b * T_N + t) * 16 + s] = (s < vl) ? acc * (1.f/32.f) : NEGV;
    }
}

// ---------------------------------------------------------------- top-8 stats, top-16 tokens, sparse combine
__global__ __launch_bounds__(256) void select_combine_kernel(
    const float* __restrict__ ssc, const float* __restrict__ tsc,
    const u16* __restrict__ vv, u16* __restrict__ out, int t0, int vld)
{
    const int tl = blockIdx.x, b = blockIdx.y;
    const int tg = t0 + tl;
    const int tid = threadIdx.x;
    const int wave = tid >> 6, lane = tid & 63;
    __shared__ float coeff[128];
    __shared__ long  rowoff[128];
    __shared__ int   sel_s[8];
    __shared__ float sel_w[8];

    if (wave == 0) {
        float cur = (lane < 16) ? ssc[((long)b * T_N + tg) * 16 + lane] : -3e38f;
        float mx0 = 0.f, ssum = 0.f, myv = -3e38f;
        int myi = 0;
        #pragma unroll
        for (int it = 0; it < 8; it++) {
            float mv = cur; int mi = lane;
            #pragma unroll
            for (int d = 1; d < 64; d <<= 1) {
                float ov = __shfl_xor(mv, d, 64);
                int   oi = __shfl_xor(mi, d, 64);
                if (ov > mv || (ov == mv && oi < mi)) { mv = ov; mi = oi; }
            }
            if (it == 0) mx0 = mv;
            ssum += __expf(mv - mx0);
            if (lane == it) { myv = mv; myi = mi; }
            if (lane == mi) cur = -3e38f;
        }
        if (lane < 8) { sel_s[lane] = myi; sel_w[lane] = __expf(myv - mx0) / ssum; }
    }
    __syncthreads();

    for (int slot = wave; slot < 8; slot += 4) {
        int s = sel_s[slot];
        float sw = sel_w[slot];
        const float* trow = tsc + (((long)b * 16 + s) * 512 + tl) * 256;
        float4 lv4 = *(const float4*)(trow + lane * 4);
        float loc[4] = { lv4.x, lv4.y, lv4.z, lv4.w };
        float mx0 = 0.f, tsum = 0.f, myv = -3e38f;
        int myi = 0;
        for (int it = 0; it < 16; it++) {
            float mv = -3e38f; int mi = 0;
            #pragma unroll
            for (int u = 0; u < 4; u++)
                if (loc[u] > mv) { mv = loc[u]; mi = lane*4 + u; }
            #pragma unroll
            for (int d = 1; d < 64; d <<= 1) {
                float ov = __shfl_xor(mv, d, 64);
                int   oi = __shfl_xor(mi, d, 64);
                if (ov > mv || (ov == mv && oi < mi)) { mv = ov; mi = oi; }
            }
            if (it == 0) mx0 = mv * (1.f/32.f);
            tsum += __expf(mv * (1.f/32.f) - mx0);
            if (lane == it) { myv = mv; myi = mi; }
            if ((mi >> 2) == lane) {
                int u = mi & 3;
                if (u == 0) loc[0] = -3e38f;
                else if (u == 1) loc[1] = -3e38f;
                else if (u == 2) loc[2] = -3e38f;
                else loc[3] = -3e38f;
            }
        }
        if (lane < 16) {
            coeff[slot * 16 + lane]  = sw * __expf(myv * (1.f/32.f) - mx0) / tsum;
            rowoff[slot * 16 + lane] = (long)((b * 16 + s) * 256 + myi) * vld;
        }
    }
    __syncthreads();

    const int d0 = tid * 4;
    float a0 = 0.f, a1 = 0.f, a2 = 0.f, a3 = 0.f;
    for (int r = 0; r < 128; r++) {
        float c = coeff[r];
        const u16* vp = vv + rowoff[r] + d0;
        u16x4 v4 = *(const u16x4*)vp;
        a0 += c * bf2f(v4[0]);
        a1 += c * bf2f(v4[1]);
        a2 += c * bf2f(v4[2]);
        a3 += c * bf2f(v4[3]);
    }
    u16x4 o4 = { f2bf(a0), f2bf(a1), f2bf(a2), f2bf(a3) };
    *(u16x4*)(out + ((long)b * T_N + tg) * 1024 + d0) = o4;
}

// ---------------------------------------------------------------- LN kernels
__device__ __forceinline__ float block_sum(float v, float* red) {
    #pragma unroll
    for (int d = 1; d < 64; d <<= 1) v += __shfl_xor(v, d, 64);
    __syncthreads();
    if ((threadIdx.x & 63) == 0) red[threadIdx.x >> 6] = v;
    __syncthreads();
    return red[0] + red[1] + red[2] + red[3];
}

__global__ __launch_bounds__(256) void ln1_kernel(
    const float* __restrict__ x, const float* __restrict__ x2,
    const float* __restrict__ intent, const float* __restrict__ g, const float* __restrict__ be,
    u16* __restrict__ yi)
{
    __shared__ float red[4];
    const long row = blockIdx.x;
    const int tid = threadIdx.x;
    const long base = row * 1024 + tid * 4;
    float4 xv = *(const float4*)(x + base);
    float4 dv = *(const float4*)(x2 + base);
    float h0 = xv.x + dv.x, h1 = xv.y + dv.y, h2 = xv.z + dv.z, h3 = xv.w + dv.w;
    float s1 = block_sum(h0 + h1 + h2 + h3, red);
    float s2 = block_sum(h0*h0 + h1*h1 + h2*h2 + h3*h3, red);
    float mean = s1 * (1.f/1024.f);
    float var = s2 * (1.f/1024.f) - mean * mean;
    float inv = rsqrtf(var + 1e-5f);
    const int c = tid * 4;
    float4 gv = *(const float4*)(g + c);
    float4 bv = *(const float4*)(be + c);
    float o0 = (h0 - mean) * inv * gv.x + bv.x;
    float o1 = (h1 - mean) * inv * gv.y + bv.y;
    float o2 = (h2 - mean) * inv * gv.z + bv.z;
    float o3 = (h3 - mean) * inv * gv.w + bv.w;
    u16x4 ob = { f2bf(o0), f2bf(o1), f2bf(o2), f2bf(o3) };
    *(u16x4*)(yi + row * 1280 + c) = ob;
    const int b = (int)(row >> 10);
    yi[row * 1280 + 1024 + tid] = f2bf(intent[b * 256 + tid]);
}

__global__ __launch_bounds__(256) void gate_ln2_kernel(
    const u16* __restrict__ yi, const float* __restrict__ y2s, const float* __restrict__ y2e,
    const float* __restrict__ Wg, const float* __restrict__ g, const float* __restrict__ be,
    float* __restrict__ z, u16* __restrict__ zbf)
{
    __shared__ float red[4];
    const long row = blockIdx.x;
    const int tid = threadIdx.x;
    const long base = row * 1024 + tid * 4;
    const int c = tid * 4;
    float4 sv = *(const float4*)(y2s + base);
    float4 ev = *(const float4*)(y2e + base);
    float4 w1 = *(const float4*)(Wg + c);
    float4 w2 = *(const float4*)(Wg + 1024 + c);
    float dot = sv.x*w1.x + sv.y*w1.y + sv.z*w1.z + sv.w*w1.w
              + ev.x*w2.x + ev.y*w2.y + ev.z*w2.z + ev.w*w2.w;
    float tot = block_sum(dot, red);
    float gate = 1.f / (1.f + __expf(-tot));
    u16x4 yv4 = *(const u16x4*)(yi + row * 1280 + c);
    float h0 = bf2f(yv4[0]) + 2.f * (gate * sv.x + (1.f - gate) * ev.x);
    float h1 = bf2f(yv4[1]) + 2.f * (gate * sv.y + (1.f - gate) * ev.y);
    float h2 = bf2f(yv4[2]) + 2.f * (gate * sv.z + (1.f - gate) * ev.z);
    float h3 = bf2f(yv4[3]) + 2.f * (gate * sv.w + (1.f - gate) * ev.w);
    float s1 = block_sum(h0 + h1 + h2 + h3, red);
    float s2 = block_sum(h0*h0 + h1*h1 + h2*h2 + h3*h3, red);
    float mean = s1 * (1.f/1024.f);
    float var = s2 * (1.f/1024.f) - mean * mean;
    float inv = rsqrtf(var + 1e-5f);
    float4 gv = *(const float4*)(g + c);
    float4 bv = *(const float4*)(be + c);
    float o0 = (h0 - mean) * inv * gv.x + bv.x;
    float o1 = (h1 - mean) * inv * gv.y + bv.y;
    float o2 = (h2 - mean) * inv * gv.z + bv.z;
    float o3 = (h3 - mean) * inv * gv.w + bv.w;
    *(float4*)(z + base) = make_float4(o0, o1, o2, o3);
    u16x4 ob = { f2bf(o0), f2bf(o1), f2bf(o2), f2bf(o3) };
    *(u16x4*)(zbf + row * 1024 + c) = ob;
}

__global__ __launch_bounds__(256) void ln3_kernel(
    const float* __restrict__ z, const float* __restrict__ f,
    const float* __restrict__ g, const float* __restrict__ be, float* __restrict__ out)
{
    __shared__ float red[4];
    const long row = blockIdx.x;
    const int tid = threadIdx.x;
    const long base = row * 1024 + tid * 4;
    float4 zv = *(const float4*)(z + base);
    float4 fv = *(const float4*)(f + base);
    float h0 = zv.x + fv.x, h1 = zv.y + fv.y, h2 = zv.z + fv.z, h3 = zv.w + fv.w;
    float s1 = block_sum(h0 + h1 + h2 + h3, red);
    float s2 = block_sum(h0*h0 + h1*h1 + h2*h2 + h3*h3, red);
    float mean = s1 * (1.f/1024.f);
    float var = s2 * (1.f/1024.f) - mean * mean;
    float inv = rsqrtf(var + 1e-5f);
    const int c = tid * 4;
    float4 gv = *(const float4*)(g + c);
    float4 bv = *(const float4*)(be + c);
    float o0 = (h0 - mean) * inv * gv.x + bv.x;
    float o1 = (h1 - mean) * inv * gv.y + bv.y;
    float o2 = (h2 - mean) * inv * gv.z + bv.z;
    float o3 = (h3 - mean) * inv * gv.w + bv.w;
    *(float4*)(out + base) = make_float4(o0, o1, o2, o3);
}

// ---------------------------------------------------------------- host
extern "C" void kernel_launch(void* const* d_in, const int* in_sizes, int n_in,
                              void* d_out, int out_size, void* d_ws, size_t ws_size,
                              hipStream_t stream)
{
    (void)in_sizes; (void)n_in; (void)out_size; (void)ws_size;
    const float* x      = (const float*)d_in[0];
    const float* stat_e = (const float*)d_in[1];
    const float* exem   = (const float*)d_in[2];
    const float* sfeat  = (const float*)d_in[3];
    const float* intent = (const float*)d_in[4];
    const float* Wg  = (const float*)d_in[19];
    const float* b1  = (const float*)d_in[21];
    const float* b2  = (const float*)d_in[23];
    const float* g1  = (const float*)d_in[24]; const float* be1 = (const float*)d_in[25];
    const float* g2  = (const float*)d_in[26]; const float* be2 = (const float*)d_in[27];
    const float* g3  = (const float*)d_in[28]; const float* be3 = (const float*)d_in[29];
    const int* svl = (const int*)d_in[30];
    const int* evl = (const int*)d_in[31];
    float* outp = (float*)d_out;

    // ---- workspace plan: 171 MB, lifetime-aliased ----
    char* base = (char*)d_ws;
    u16*  bufA  = (u16*)(base + 0*MB);        // 8MB: xbf / attn-outs / y2s_pre
    u16*  qkv1  = (u16*)(base + 8*MB);        // 24MB fused [4096,3072] (phase 3)
    float* x2a  = (float*)(base + 8*MB);      // 16MB (after flash1)
    u16*  kv2   = (u16*)(base + 8*MB);        // 16MB fused [4096,2048] (phase 5)
    u16*  w1t   = (u16*)(base + 8*MB);        // 8MB (phase 7)
    u16*  w2t   = (u16*)(base + 16*MB);       // 8MB (phase 7)
    u16*  yibf  = (u16*)(base + 32*MB);       // 10MB [4096,1280]
    u16*  buf3  = (u16*)(base + 42*MB);       // 24MB fused qs|qt|q2 [4096,3072]
    u16*  zbf   = (u16*)(base + 42*MB);       // 8MB (after flash2)
    u16*  sebf  = (u16*)(base + 66*MB);       // 32MB stat_enc bf16 / tsc-half fp32 / ffn hidden
    float* tsch = (float*)(base + 66*MB);
    u16*  hid   = (u16*)(base + 66*MB);
    u16*  ktvv  = (u16*)(base + 98*MB);       // 64MB fused [16384,2048]
    float* y2sf = (float*)(base + 98*MB);     // 16MB (after select)
    float* ffn2f= (float*)(base + 98*MB);     // 16MB (after gate_ln2)
    u16*  exbf  = (u16*)(base + 114*MB);      // 8MB
    float* y2ef = (float*)(base + 122*MB);    // 16MB
    float* zf   = (float*)(base + 138*MB);    // 16MB
    u16*  sfbf  = (u16*)(base + 162*MB);                  // 128KB
    u16*  ksbf  = (u16*)(base + 162*MB + 256*1024);       // 128KB
    float* sscf = (float*)(base + 162*MB + 512*1024);     // 256KB
    char* wpool = base + 163*MB;              // 8MB rotating weight pool (total 171MB)

    dim3 blk(256);
    auto cast = [&](const float* s, u16* d, long n) {
        cast_bf16_kernel<<<dim3((unsigned)((n/4 + 255) / 256)), blk, 0, stream>>>(s, d, n);
    };
    auto g_n = [&](const u16* A, const u16* Bt, u16* C, int M, int N, int K,
                   int lda, int ldb, int ldc) {
        gemm_bt<u16,false,false><<<dim3(N/128, (M+127)/128, 1), blk, 0, stream>>>(
            A, Bt, C, nullptr, M, N, K, lda, ldb, ldc, 1, 0, 0, 0);
    };
    auto g_f = [&](const u16* A, const u16* Bt, float* C, int M, int N, int K,
                   int lda, int ldb, int ldc) {
        gemm_bt<float,false,false><<<dim3(N/128, (M+127)/128, 1), blk, 0, stream>>>(
            A, Bt, C, nullptr, M, N, K, lda, ldb, ldc, 1, 0, 0, 0);
    };

    // ---- phase 3: self-attention ----
    u16* wqkv1t = (u16*)wpool;                       // [3072,1024] stacked
    u16* wo1t   = (u16*)(wpool) + 3L*1024*1024;
    {
        P6 pp{};
        pp.s[0]=(const float*)d_in[5]; pp.d[0]=wqkv1t;
        pp.s[1]=(const float*)d_in[6]; pp.d[1]=wqkv1t + 1L*1024*1024;
        pp.s[2]=(const float*)d_in[7]; pp.d[2]=wqkv1t + 2L*1024*1024;
        pp.s[3]=(const float*)d_in[8]; pp.d[3]=wo1t;
        transpose_cast_batch<<<dim3(32, 32, 4), blk, 0, stream>>>(pp, 1024, 1024);
    }
    cast(x, bufA, 4096L*1024);
    g_n(bufA, wqkv1t, qkv1, 4096, 3072, 1024, 1024, 1024, 3072);
    flash_attn_kernel<true><<<dim3(16, 16, 4), blk, 0, stream>>>(
        qkv1, qkv1 + 1024, qkv1 + 2048, nullptr, bufA, 3072, 3072, 3072);
    g_f(bufA, wo1t, x2a, 4096, 1024, 1024, 1024, 1024, 1024);
    ln1_kernel<<<dim3(4096), blk, 0, stream>>>(x, x2a, intent, g1, be1, yibf);

    // ---- phase 4: selective hierarchical attention ----
    // A-set: [Wq_stat; Wq_token; Wq2] -> pool, each [1024,1280]
    u16* wq3t = (u16*)wpool;
    {
        P6 pp{};
        pp.s[0]=(const float*)d_in[9];  pp.d[0]=wq3t;
        pp.s[1]=(const float*)d_in[10]; pp.d[1]=wq3t + 1L*1024*1280;
        pp.s[2]=(const float*)d_in[15]; pp.d[2]=wq3t + 2L*1024*1280;
        transpose_cast_batch<<<dim3(32, 40, 3), blk, 0, stream>>>(pp, 1280, 1024);
    }
    g_n(yibf, wq3t, buf3, 4096, 3072, 1280, 1280, 1280, 3072);   // qs|qt|q2
    // B-set: wkst + [wktt|wvst]
    u16* wkst = (u16*)wpool;
    u16* wkv  = (u16*)(wpool) + 1L*1024*1024;
    {
        P6 pp{};
        pp.s[0]=(const float*)d_in[11]; pp.d[0]=wkst;
        pp.s[1]=(const float*)d_in[12]; pp.d[1]=wkv;
        pp.s[2]=(const float*)d_in[13]; pp.d[2]=wkv + 1L*1024*1024;
        transpose_cast_batch<<<dim3(32, 32, 3), blk, 0, stream>>>(pp, 1024, 1024);
    }
    cast(sfeat, sfbf, 64L*1024);
    cast(stat_e, sebf, 16384L*1024);
    g_n(sfbf, wkst, ksbf, 64, 1024, 1024, 1024, 1024, 1024);
    g_n(sebf, wkv, ktvv, 16384, 2048, 1024, 1024, 1024, 2048);   // kt|vv
    ssc_kernel<<<dim3(1024, 4), blk, 0, stream>>>(buf3, ksbf, svl, sscf, 3072);
    for (int hh = 0; hh < 2; hh++) {
        long t0 = hh * 512;
        gemm_bt<float,false,false><<<dim3(2, 4, 64), blk, 0, stream>>>(
            buf3 + 1024 + t0*3072, ktvv, tsch, nullptr, 512, 256, 1024,
            3072, 2048, 256, 16, (long)T_N*3072, 256L*2048, 512L*256);
        select_combine_kernel<<<dim3(512, 4), blk, 0, stream>>>(
            sscf, tsch, ktvv + 1024, bufA, (int)t0, 2048);
    }
    // C-set: wost + [wk2|wv2] + wo2t
    u16* wost = (u16*)wpool;
    u16* wkv2 = (u16*)(wpool) + 1L*1024*1024;
    u16* wo2t = (u16*)(wpool) + 3L*1024*1024;
    {
        P6 pp{};
        pp.s[0]=(const float*)d_in[14]; pp.d[0]=wost;
        pp.s[1]=(const float*)d_in[16]; pp.d[1]=wkv2;
        pp.s[2]=(const float*)d_in[17]; pp.d[2]=wkv2 + 1L*1024*1024;
        pp.s[3]=(const float*)d_in[18]; pp.d[3]=wo2t;
        transpose_cast_batch<<<dim3(32, 32, 4), blk, 0, stream>>>(pp, 1024, 1024);
    }
    g_f(bufA, wost, y2sf, 4096, 1024, 1024, 1024, 1024, 1024);

    // ---- phase 5: exemplar cross-attention ----
    cast(exem, exbf, 4096L*1024);
    g_n(exbf, wkv2, kv2, 4096, 2048, 1024, 1024, 1024, 2048);    // k2|v2
    flash_attn_kernel<false><<<dim3(16, 16, 4), blk, 0, stream>>>(
        buf3 + 2048, kv2, kv2 + 1024, evl, bufA, 3072, 2048, 2048);
    g_f(bufA, wo2t, y2ef, 4096, 1024, 1024, 1024, 1024, 1024);

    // ---- phase 6: gate + LN2 ----
    gate_ln2_kernel<<<dim3(4096), blk, 0, stream>>>(yibf, y2sf, y2ef, Wg, g2, be2, zf, zbf);

    // ---- phase 7: FFN ----
    {
        P6 pp{}; pp.s[0] = (const float*)d_in[20]; pp.d[0] = w1t;
        transpose_cast_batch<<<dim3(128, 32, 1), blk, 0, stream>>>(pp, 1024, 4096);
    }
    {
        P6 pp{}; pp.s[0] = (const float*)d_in[22]; pp.d[0] = w2t;
        transpose_cast_batch<<<dim3(32, 128, 1), blk, 0, stream>>>(pp, 4096, 1024);
    }
    gemm_bt<u16,true,true><<<dim3(32, 32, 1), blk, 0, stream>>>(
        zbf, w1t, hid, b1, 4096, 4096, 1024, 1024, 1024, 4096, 1, 0, 0, 0);
    gemm_bt<float,false,true><<<dim3(8, 32, 1), blk, 0, stream>>>(
        hid, w2t, ffn2f, b2, 4096, 1024, 4096, 4096, 4096, 1024, 1, 0, 0, 0);

    // ---- phase 8: final LN ----
    ln3_kernel<<<dim3(4096), blk, 0, stream>>>(zf, ffn2f, g3, be3, outp);
}

// Round 4
// 1031.870 us; speedup vs baseline: 1.2844x; 1.2844x over previous
//
#include <hip/hip_runtime.h>

typedef unsigned short u16;
typedef short s16x8 __attribute__((ext_vector_type(8)));
typedef u16 u16x4 __attribute__((ext_vector_type(4)));
typedef float f32x4 __attribute__((ext_vector_type(4)));

#define T_N   1024
#define NEGV  -1e6f
#define MB    (1L << 20)

__device__ __forceinline__ u16 f2bf(float f) {
    unsigned u = __float_as_uint(f);
    u += 0x7fffu + ((u >> 16) & 1u);     // RNE
    return (u16)(u >> 16);
}
__device__ __forceinline__ float bf2f(u16 h) {
    return __uint_as_float(((unsigned)h) << 16);
}
__device__ __forceinline__ f32x4 mfma16(s16x8 a, s16x8 b, f32x4 c) {
    return __builtin_amdgcn_mfma_f32_16x16x32_bf16(a, b, c, 0, 0, 0);
}
// async global->LDS, 16B per lane; LDS dest = wave-uniform base + lane*16 (m97/m104)
__device__ __forceinline__ void gll16(const u16* g, u16* l) {
    __builtin_amdgcn_global_load_lds((const __attribute__((address_space(1))) void*)g,
                                     (__attribute__((address_space(3))) void*)l, 16, 0, 0);
}

// ---------------------------------------------------------------- transpose+cast
struct P6 { const float* s[6]; u16* d[6]; };

__global__ __launch_bounds__(256) void transpose_cast_batch(P6 pp, int K, int N) {
    const float* __restrict__ src = pp.s[blockIdx.z];
    u16* __restrict__ dst = pp.d[blockIdx.z];
    __shared__ float tile[32][33];
    int nb = blockIdx.x * 32, kb = blockIdx.y * 32;
    int tx = threadIdx.x & 31, ty = threadIdx.x >> 5;   // ty 0..7
    #pragma unroll
    for (int i = 0; i < 4; i++)
        tile[ty + 8*i][tx] = src[(long)(kb + ty + 8*i) * N + nb + tx];
    __syncthreads();
    #pragma unroll
    for (int i = 0; i < 4; i++)
        dst[(long)(nb + ty + 8*i) * K + kb + tx] = f2bf(tile[tx][ty + 8*i]);
}

__global__ __launch_bounds__(256) void cast_bf16_kernel(const float* __restrict__ src,
                                                        u16* __restrict__ dst, long n) {
    long i = ((long)blockIdx.x * 256 + threadIdx.x) * 4;
    if (i >= n) return;
    float4 v = *(const float4*)(src + i);
    u16x4 o = { f2bf(v.x), f2bf(v.y), f2bf(v.z), f2bf(v.w) };
    *(u16x4*)(dst + i) = o;
}

// ---------------------------------------------------------------- GEMM: C[M,N] = A[M,K] * Bt[N,K]^T
// m97-style staging: global_load_lds width-16, COALESCED (4 lanes cover one
// row's 64B k-chunk), LDS unpadded row-major [128][32] (required by the
// wave-uniform-base+lane*16 DMA constraint). Fragment ds_read_b128 from this
// layout uses every bank exactly 8x per wave = port minimum (conflict-free).
// 128x128 tile, BK=32, 4 waves x 4x4 of 16x16x32 mfma. lda/ldb/ldc in elements.
template<typename OutT, bool RELU, bool HAS_BIAS>
__global__ __launch_bounds__(256) void gemm_bt(
    const u16* __restrict__ A, const u16* __restrict__ Bt, OutT* __restrict__ C,
    const float* __restrict__ bias, int M, int N, int K,
    int lda, int ldb, int ldc,
    int batchDivA, long sA, long sB, long sC)
{
    A  += (long)(blockIdx.z / batchDivA) * sA;
    Bt += (long)blockIdx.z * sB;
    C  += (long)blockIdx.z * sC;
    __shared__ __align__(16) u16 As[4096];   // [128][32] row-major, 8 KB
    __shared__ __align__(16) u16 Bs[4096];
    const int tid = threadIdx.x;
    const int wave = tid >> 6, lane = tid & 63;
    const int quad = lane >> 4, l16 = lane & 15;
    const int wr = (wave >> 1) * 64, wc = (wave & 1) * 64;
    const long row0 = (long)blockIdx.y * 128, col0 = (long)blockIdx.x * 128;

    f32x4 acc[4][4] = {};

    // wave w stages tile rows [w*32, w*32+32): 2 instrs of 16 rows each.
    // lane l covers row (l>>2), k-bytes (l&3)*16 -> 64B contiguous per row.
    const int l4r = lane >> 2;
    const int l4c = (lane & 3) * 8;
    const int ra = wave * 32 + l4r;
    const u16* Ap0 = A + (row0 + ra) * (long)lda + l4c;
    const u16* Ap1 = Ap0 + 16L * lda;
    const u16* Bp0 = Bt + (col0 + ra) * (long)ldb + l4c;
    const u16* Bp1 = Bp0 + 16L * ldb;
    u16* AsW0 = &As[(wave * 32) * 32];
    u16* AsW1 = &As[(wave * 32 + 16) * 32];
    u16* BsW0 = &Bs[(wave * 32) * 32];
    u16* BsW1 = &Bs[(wave * 32 + 16) * 32];
    // all M in this model are multiples of 16 -> wave-uniform validity
    const bool aok0 = (row0 + wave * 32) < M;
    const bool aok1 = (row0 + wave * 32 + 16) < M;

    for (int k0 = 0; k0 < K; k0 += 32) {
        __syncthreads();                       // prev-iter LDS reads done
        if (aok0) gll16(Ap0 + k0, AsW0);
        if (aok1) gll16(Ap1 + k0, AsW1);
        gll16(Bp0 + k0, BsW0);
        gll16(Bp1 + k0, BsW1);
        __syncthreads();                       // vmcnt drained before barrier
        s16x8 af[4], bfr[4];
        #pragma unroll
        for (int i = 0; i < 4; i++)
            af[i]  = *(const s16x8*)&As[(wr + i*16 + l16) * 32 + quad*8];
        #pragma unroll
        for (int j = 0; j < 4; j++)
            bfr[j] = *(const s16x8*)&Bs[(wc + j*16 + l16) * 32 + quad*8];
        #pragma unroll
        for (int i = 0; i < 4; i++)
            #pragma unroll
            for (int j = 0; j < 4; j++)
                acc[i][j] = mfma16(af[i], bfr[j], acc[i][j]);
    }

    #pragma unroll
    for (int i = 0; i < 4; i++) {
        long row = row0 + wr + i*16 + quad*4;
        #pragma unroll
        for (int j = 0; j < 4; j++) {
            long col = col0 + wc + j*16 + l16;
            float bv = 0.f;
            if constexpr (HAS_BIAS) bv = bias[col];
            #pragma unroll
            for (int r = 0; r < 4; r++) {
                if (row + r < M) {
                    float v = acc[i][j][r] + bv;
                    if constexpr (RELU) v = fmaxf(v, 0.f);
                    if constexpr (sizeof(OutT) == 2) C[(row + r) * (long)ldc + col] = f2bf(v);
                    else                             C[(row + r) * (long)ldc + col] = v;
                }
            }
        }
    }
}

// ---------------------------------------------------------------- flash attention (dh=64, H=16)
template<bool CAUSAL>
__global__ __launch_bounds__(256) void flash_attn_kernel(
    const u16* __restrict__ Q, const u16* __restrict__ Kg, const u16* __restrict__ Vg,
    const int* __restrict__ valid_len, u16* __restrict__ O,
    int qld, int kld, int vld)
{
    const int h = blockIdx.y, b = blockIdx.z;
    const int qt0 = blockIdx.x * 64;
    const int tid = threadIdx.x;
    const int wave = tid >> 6, lane = tid & 63;
    const int quad = lane >> 4, l16 = lane & 15;

    __shared__ __align__(16) u16 Qs[64][72];
    __shared__ __align__(16) u16 Ks[64][72];
    __shared__ __align__(16) u16 Vt[64][72];
    __shared__ __align__(16) u16 Ps[4][16][72];

    const int sr = tid >> 2, scc = (tid & 3) * 16;
    {
        const u16* qp = Q + ((long)b * T_N + qt0 + sr) * qld + h * 64 + scc;
        *(s16x8*)&Qs[sr][scc]     = *(const s16x8*)qp;
        *(s16x8*)&Qs[sr][scc + 8] = *(const s16x8*)(qp + 8);
    }
    float m_i[4] = {-1e30f, -1e30f, -1e30f, -1e30f};
    float l_i[4] = {0.f, 0.f, 0.f, 0.f};
    f32x4 o_acc[4] = {};

    int vl = 0, kend;
    if (CAUSAL) kend = qt0 + 64;
    else { vl = valid_len[b]; kend = (vl + 63) & ~63; }

    for (int kv0 = 0; kv0 < kend; kv0 += 64) {
        __syncthreads();
        {
            const u16* kp = Kg + ((long)b * T_N + kv0 + sr) * kld + h * 64 + scc;
            *(s16x8*)&Ks[sr][scc]     = *(const s16x8*)kp;
            *(s16x8*)&Ks[sr][scc + 8] = *(const s16x8*)(kp + 8);
            const u16* vp = Vg + ((long)b * T_N + kv0 + sr) * vld + h * 64 + scc;
            s16x8 v0 = *(const s16x8*)vp;
            s16x8 v1 = *(const s16x8*)(vp + 8);
            #pragma unroll
            for (int j = 0; j < 8; j++) {
                Vt[scc + j][sr]     = (u16)v0[j];
                Vt[scc + 8 + j][sr] = (u16)v1[j];
            }
        }
        __syncthreads();
        f32x4 sc[4] = {};
        #pragma unroll
        for (int kk = 0; kk < 64; kk += 32) {
            s16x8 aq = *(const s16x8*)&Qs[wave*16 + l16][kk + quad*8];
            #pragma unroll
            for (int j = 0; j < 4; j++) {
                s16x8 bk = *(const s16x8*)&Ks[j*16 + l16][kk + quad*8];
                sc[j] = mfma16(aq, bk, sc[j]);
            }
        }
        const int qrow = qt0 + wave*16 + quad*4;
        #pragma unroll
        for (int j = 0; j < 4; j++) {
            int kcol = kv0 + j*16 + l16;
            #pragma unroll
            for (int r = 0; r < 4; r++) {
                float s = sc[j][r] * 0.125f;
                bool ok = CAUSAL ? (kcol <= qrow + r) : (kcol < vl);
                sc[j][r] = ok ? s : -1e30f;
            }
        }
        float alpha[4];
        #pragma unroll
        for (int r = 0; r < 4; r++) {
            float mx = fmaxf(fmaxf(sc[0][r], sc[1][r]), fmaxf(sc[2][r], sc[3][r]));
            #pragma unroll
            for (int d = 1; d < 16; d <<= 1) mx = fmaxf(mx, __shfl_xor(mx, d, 64));
            float mn = fmaxf(m_i[r], mx);
            alpha[r] = __expf(m_i[r] - mn);
            m_i[r] = mn;
        }
        float rsum[4] = {0.f, 0.f, 0.f, 0.f};
        #pragma unroll
        for (int j = 0; j < 4; j++)
            #pragma unroll
            for (int r = 0; r < 4; r++) {
                float pv = __expf(sc[j][r] - m_i[r]);
                sc[j][r] = pv;
                rsum[r] += pv;
            }
        #pragma unroll
        for (int r = 0; r < 4; r++) {
            #pragma unroll
            for (int d = 1; d < 16; d <<= 1) rsum[r] += __shfl_xor(rsum[r], d, 64);
            l_i[r] = l_i[r] * alpha[r] + rsum[r];
        }
        #pragma unroll
        for (int j = 0; j < 4; j++)
            #pragma unroll
            for (int r = 0; r < 4; r++)
                Ps[wave][quad*4 + r][j*16 + l16] = f2bf(sc[j][r]);
        #pragma unroll
        for (int j2 = 0; j2 < 4; j2++)
            #pragma unroll
            for (int r = 0; r < 4; r++)
                o_acc[j2][r] *= alpha[r];
        __syncthreads();
        #pragma unroll
        for (int kk = 0; kk < 64; kk += 32) {
            s16x8 ap = *(const s16x8*)&Ps[wave][l16][kk + quad*8];
            #pragma unroll
            for (int j2 = 0; j2 < 4; j2++) {
                s16x8 bv = *(const s16x8*)&Vt[j2*16 + l16][kk + quad*8];
                o_acc[j2] = mfma16(ap, bv, o_acc[j2]);
            }
        }
    }
    #pragma unroll
    for (int j2 = 0; j2 < 4; j2++) {
        #pragma unroll
        for (int r = 0; r < 4; r++) {
            float v = o_acc[j2][r] / l_i[r];
            long row = (long)b * T_N + qt0 + wave*16 + quad*4 + r;
            O[row * 1024 + h*64 + j2*16 + l16] = f2bf(v);
        }
    }
}

// ---------------------------------------------------------------- ssc[b,t,s] = qs.ks/32 (masked)
__global__ __launch_bounds__(256) void ssc_kernel(
    const u16* __restrict__ qs, const u16* __restrict__ ks,
    const int* __restrict__ svl, float* __restrict__ ssc, int qld)
{
    const int t = blockIdx.x, b = blockIdx.y;
    const int wave = threadIdx.x >> 6, lane = threadIdx.x & 63;
    const u16* qrow = qs + ((long)b * T_N + t) * qld + lane * 16;
    const int vl = svl[b];
    for (int s = wave; s < 16; s += 4) {
        const u16* krow = ks + ((long)b * 16 + s) * 1024 + lane * 16;
        float acc = 0.f;
        #pragma unroll
        for (int seg = 0; seg < 2; seg++) {
            s16x8 qv = *(const s16x8*)(qrow + seg*8);
            s16x8 kv = *(const s16x8*)(krow + seg*8);
            #pragma unroll
            for (int j = 0; j < 8; j++) acc += bf2f((u16)qv[j]) * bf2f((u16)kv[j]);
        }
        #pragma unroll
        for (int d = 1; d < 64; d <<= 1) acc += __shfl_xor(acc, d, 64);
        if (lane == 0)
            ssc[((long)b * T_N + t) * 16 + s] = (s < vl) ? acc * (1.f/32.f) : NEGV;
    }
}

// ---------------------------------------------------------------- top-8 stats, top-16 tokens, sparse combine
__global__ __launch_bounds__(256) void select_combine_kernel(
    const float* __restrict__ ssc, const float* __restrict__ tsc,
    const u16* __restrict__ vv, u16* __restrict__ out, int t0, int vld)
{
    const int tl = blockIdx.x, b = blockIdx.y;
    const int tg = t0 + tl;
    const int tid = threadIdx.x;
    const int wave = tid >> 6, lane = tid & 63;
    __shared__ float coeff[128];
    __shared__ long  rowoff[128];
    __shared__ int   sel_s[8];
    __shared__ float sel_w[8];

    if (wave == 0) {
        float cur = (lane < 16) ? ssc[((long)b * T_N + tg) * 16 + lane] : -3e38f;
        float mx0 = 0.f, ssum = 0.f, myv = -3e38f;
        int myi = 0;
        #pragma unroll
        for (int it = 0; it < 8; it++) {
            float mv = cur; int mi = lane;
            #pragma unroll
            for (int d = 1; d < 64; d <<= 1) {
                float ov = __shfl_xor(mv, d, 64);
                int   oi = __shfl_xor(mi, d, 64);
                if (ov > mv || (ov == mv && oi < mi)) { mv = ov; mi = oi; }
            }
            if (it == 0) mx0 = mv;
            ssum += __expf(mv - mx0);
            if (lane == it) { myv = mv; myi = mi; }
            if (lane == mi) cur = -3e38f;
        }
        if (lane < 8) { sel_s[lane] = myi; sel_w[lane] = __expf(myv - mx0) / ssum; }
    }
    __syncthreads();

    for (int slot = wave; slot < 8; slot += 4) {
        int s = sel_s[slot];
        float sw = sel_w[slot];
        const float* trow = tsc + (((long)b * 16 + s) * 512 + tl) * 256;
        float4 lv4 = *(const float4*)(trow + lane * 4);
        float loc[4] = { lv4.x, lv4.y, lv4.z, lv4.w };
        float mx0 = 0.f, tsum = 0.f, myv = -3e38f;
        int myi = 0;
        for (int it = 0; it < 16; it++) {
            float mv = -3e38f; int mi = 0;
            #pragma unroll
            for (int u = 0; u < 4; u++)
                if (loc[u] > mv) { mv = loc[u]; mi = lane*4 + u; }
            #pragma unroll
            for (int d = 1; d < 64; d <<= 1) {
                float ov = __shfl_xor(mv, d, 64);
                int   oi = __shfl_xor(mi, d, 64);
                if (ov > mv || (ov == mv && oi < mi)) { mv = ov; mi = oi; }
            }
            if (it == 0) mx0 = mv * (1.f/32.f);
            tsum += __expf(mv * (1.f/32.f) - mx0);
            if (lane == it) { myv = mv; myi = mi; }
            if ((mi >> 2) == lane) {
                int u = mi & 3;
                if (u == 0) loc[0] = -3e38f;
                else if (u == 1) loc[1] = -3e38f;
                else if (u == 2) loc[2] = -3e38f;
                else loc[3] = -3e38f;
            }
        }
        if (lane < 16) {
            coeff[slot * 16 + lane]  = sw * __expf(myv * (1.f/32.f) - mx0) / tsum;
            rowoff[slot * 16 + lane] = (long)((b * 16 + s) * 256 + myi) * vld;
        }
    }
    __syncthreads();

    const int d0 = tid * 4;
    float a0 = 0.f, a1 = 0.f, a2 = 0.f, a3 = 0.f;
    for (int r = 0; r < 128; r++) {
        float c = coeff[r];
        const u16* vp = vv + rowoff[r] + d0;
        u16x4 v4 = *(const u16x4*)vp;
        a0 += c * bf2f(v4[0]);
        a1 += c * bf2f(v4[1]);
        a2 += c * bf2f(v4[2]);
        a3 += c * bf2f(v4[3]);
    }
    u16x4 o4 = { f2bf(a0), f2bf(a1), f2bf(a2), f2bf(a3) };
    *(u16x4*)(out + ((long)b * T_N + tg) * 1024 + d0) = o4;
}

// ---------------------------------------------------------------- LN kernels
__device__ __forceinline__ float block_sum(float v, float* red) {
    #pragma unroll
    for (int d = 1; d < 64; d <<= 1) v += __shfl_xor(v, d, 64);
    __syncthreads();
    if ((threadIdx.x & 63) == 0) red[threadIdx.x >> 6] = v;
    __syncthreads();
    return red[0] + red[1] + red[2] + red[3];
}

__global__ __launch_bounds__(256) void ln1_kernel(
    const float* __restrict__ x, const float* __restrict__ x2,
    const float* __restrict__ intent, const float* __restrict__ g, const float* __restrict__ be,
    u16* __restrict__ yi)
{
    __shared__ float red[4];
    const long row = blockIdx.x;
    const int tid = threadIdx.x;
    const long base = row * 1024 + tid * 4;
    float4 xv = *(const float4*)(x + base);
    float4 dv = *(const float4*)(x2 + base);
    float h0 = xv.x + dv.x, h1 = xv.y + dv.y, h2 = xv.z + dv.z, h3 = xv.w + dv.w;
    float s1 = block_sum(h0 + h1 + h2 + h3, red);
    float s2 = block_sum(h0*h0 + h1*h1 + h2*h2 + h3*h3, red);
    float mean = s1 * (1.f/1024.f);
    float var = s2 * (1.f/1024.f) - mean * mean;
    float inv = rsqrtf(var + 1e-5f);
    const int c = tid * 4;
    float4 gv = *(const float4*)(g + c);
    float4 bv = *(const float4*)(be + c);
    float o0 = (h0 - mean) * inv * gv.x + bv.x;
    float o1 = (h1 - mean) * inv * gv.y + bv.y;
    float o2 = (h2 - mean) * inv * gv.z + bv.z;
    float o3 = (h3 - mean) * inv * gv.w + bv.w;
    u16x4 ob = { f2bf(o0), f2bf(o1), f2bf(o2), f2bf(o3) };
    *(u16x4*)(yi + row * 1280 + c) = ob;
    const int b = (int)(row >> 10);
    yi[row * 1280 + 1024 + tid] = f2bf(intent[b * 256 + tid]);
}

__global__ __launch_bounds__(256) void gate_ln2_kernel(
    const u16* __restrict__ yi, const float* __restrict__ y2s, const float* __restrict__ y2e,
    const float* __restrict__ Wg, const float* __restrict__ g, const float* __restrict__ be,
    float* __restrict__ z, u16* __restrict__ zbf)
{
    __shared__ float red[4];
    const long row = blockIdx.x;
    const int tid = threadIdx.x;
    const long base = row * 1024 + tid * 4;
    const int c = tid * 4;
    float4 sv = *(const float4*)(y2s + base);
    float4 ev = *(const float4*)(y2e + base);
    float4 w1 = *(const float4*)(Wg + c);
    float4 w2 = *(const float4*)(Wg + 1024 + c);
    float dot = sv.x*w1.x + sv.y*w1.y + sv.z*w1.z + sv.w*w1.w
              + ev.x*w2.x + ev.y*w2.y + ev.z*w2.z + ev.w*w2.w;
    float tot = block_sum(dot, red);
    float gate = 1.f / (1.f + __expf(-tot));
    u16x4 yv4 = *(const u16x4*)(yi + row * 1280 + c);
    float h0 = bf2f(yv4[0]) + 2.f * (gate * sv.x + (1.f - gate) * ev.x);
    float h1 = bf2f(yv4[1]) + 2.f * (gate * sv.y + (1.f - gate) * ev.y);
    float h2 = bf2f(yv4[2]) + 2.f * (gate * sv.z + (1.f - gate) * ev.z);
    float h3 = bf2f(yv4[3]) + 2.f * (gate * sv.w + (1.f - gate) * ev.w);
    float s1 = block_sum(h0 + h1 + h2 + h3, red);
    float s2 = block_sum(h0*h0 + h1*h1 + h2*h2 + h3*h3, red);
    float mean = s1 * (1.f/1024.f);
    float var = s2 * (1.f/1024.f) - mean * mean;
    float inv = rsqrtf(var + 1e-5f);
    float4 gv = *(const float4*)(g + c);
    float4 bv = *(const float4*)(be + c);
    float o0 = (h0 - mean) * inv * gv.x + bv.x;
    float o1 = (h1 - mean) * inv * gv.y + bv.y;
    float o2 = (h2 - mean) * inv * gv.z + bv.z;
    float o3 = (h3 - mean) * inv * gv.w + bv.w;
    *(float4*)(z + base) = make_float4(o0, o1, o2, o3);
    u16x4 ob = { f2bf(o0), f2bf(o1), f2bf(o2), f2bf(o3) };
    *(u16x4*)(zbf + row * 1024 + c) = ob;
}

// final LN over z + (p0 + p1 + b2)  — FFN2 split-K partials fused here
__global__ __launch_bounds__(256) void ln3_kernel(
    const float* __restrict__ z, const float* __restrict__ p0, const float* __restrict__ p1,
    const float* __restrict__ b2,
    const float* __restrict__ g, const float* __restrict__ be, float* __restrict__ out)
{
    __shared__ float red[4];
    const long row = blockIdx.x;
    const int tid = threadIdx.x;
    const long base = row * 1024 + tid * 4;
    const int c = tid * 4;
    float4 zv = *(const float4*)(z + base);
    float4 f0 = *(const float4*)(p0 + base);
    float4 f1 = *(const float4*)(p1 + base);
    float4 bb = *(const float4*)(b2 + c);
    float h0 = zv.x + f0.x + f1.x + bb.x;
    float h1 = zv.y + f0.y + f1.y + bb.y;
    float h2 = zv.z + f0.z + f1.z + bb.z;
    float h3 = zv.w + f0.w + f1.w + bb.w;
    float s1 = block_sum(h0 + h1 + h2 + h3, red);
    float s2 = block_sum(h0*h0 + h1*h1 + h2*h2 + h3*h3, red);
    float mean = s1 * (1.f/1024.f);
    float var = s2 * (1.f/1024.f) - mean * mean;
    float inv = rsqrtf(var + 1e-5f);
    float4 gv = *(const float4*)(g + c);
    float4 bv = *(const float4*)(be + c);
    float o0 = (h0 - mean) * inv * gv.x + bv.x;
    float o1 = (h1 - mean) * inv * gv.y + bv.y;
    float o2 = (h2 - mean) * inv * gv.z + bv.z;
    float o3 = (h3 - mean) * inv * gv.w + bv.w;
    *(float4*)(out + base) = make_float4(o0, o1, o2, o3);
}

// ---------------------------------------------------------------- host
extern "C" void kernel_launch(void* const* d_in, const int* in_sizes, int n_in,
                              void* d_out, int out_size, void* d_ws, size_t ws_size,
                              hipStream_t stream)
{
    (void)in_sizes; (void)n_in; (void)out_size; (void)ws_size;
    const float* x      = (const float*)d_in[0];
    const float* stat_e = (const float*)d_in[1];
    const float* exem   = (const float*)d_in[2];
    const float* sfeat  = (const float*)d_in[3];
    const float* intent = (const float*)d_in[4];
    const float* Wg  = (const float*)d_in[19];
    const float* b1  = (const float*)d_in[21];
    const float* b2  = (const float*)d_in[23];
    const float* g1  = (const float*)d_in[24]; const float* be1 = (const float*)d_in[25];
    const float* g2  = (const float*)d_in[26]; const float* be2 = (const float*)d_in[27];
    const float* g3  = (const float*)d_in[28]; const float* be3 = (const float*)d_in[29];
    const int* svl = (const int*)d_in[30];
    const int* evl = (const int*)d_in[31];
    float* outp = (float*)d_out;

    // ---- workspace plan: 171 MB, lifetime-aliased ----
    char* base = (char*)d_ws;
    u16*  bufA  = (u16*)(base + 0*MB);        // 8MB: xbf / attn-outs / y2s_pre
    u16*  qkv1  = (u16*)(base + 8*MB);        // 24MB fused [4096,3072] (phase 3)
    float* x2a  = (float*)(base + 8*MB);      // 16MB (after flash1)
    u16*  kv2   = (u16*)(base + 8*MB);        // 16MB fused [4096,2048] (phase 5)
    u16*  w1t   = (u16*)(base + 8*MB);        // 8MB (phase 7)
    u16*  w2t   = (u16*)(base + 16*MB);       // 8MB (phase 7)
    u16*  yibf  = (u16*)(base + 32*MB);       // 10MB [4096,1280]
    u16*  buf3  = (u16*)(base + 42*MB);       // 24MB fused qs|qt|q2 [4096,3072]
    u16*  zbf   = (u16*)(base + 42*MB);       // 8MB (after flash2)
    u16*  sebf  = (u16*)(base + 66*MB);       // 32MB stat_enc bf16 / tsc-half fp32 / ffn hidden
    float* tsch = (float*)(base + 66*MB);
    u16*  hid   = (u16*)(base + 66*MB);
    u16*  ktvv  = (u16*)(base + 98*MB);       // 64MB fused [16384,2048]
    float* y2sf = (float*)(base + 98*MB);     // 16MB (after select)
    float* p0f  = (float*)(base + 98*MB);     // 32MB FFN2 partials (after gate_ln2; y2ef dead)
    u16*  exbf  = (u16*)(base + 114*MB);      // 8MB
    float* y2ef = (float*)(base + 122*MB);    // 16MB
    float* zf   = (float*)(base + 138*MB);    // 16MB
    u16*  sfbf  = (u16*)(base + 162*MB);                  // 128KB
    u16*  ksbf  = (u16*)(base + 162*MB + 256*1024);       // 128KB
    float* sscf = (float*)(base + 162*MB + 512*1024);     // 256KB
    char* wpool = base + 163*MB;              // 8MB rotating weight pool (total 171MB)

    dim3 blk(256);
    auto cast = [&](const float* s, u16* d, long n) {
        cast_bf16_kernel<<<dim3((unsigned)((n/4 + 255) / 256)), blk, 0, stream>>>(s, d, n);
    };
    auto g_n = [&](const u16* A, const u16* Bt, u16* C, int M, int N, int K,
                   int lda, int ldb, int ldc) {
        gemm_bt<u16,false,false><<<dim3(N/128, (M+127)/128, 1), blk, 0, stream>>>(
            A, Bt, C, nullptr, M, N, K, lda, ldb, ldc, 1, 0, 0, 0);
    };
    auto g_f = [&](const u16* A, const u16* Bt, float* C, int M, int N, int K,
                   int lda, int ldb, int ldc) {
        gemm_bt<float,false,false><<<dim3(N/128, (M+127)/128, 1), blk, 0, stream>>>(
            A, Bt, C, nullptr, M, N, K, lda, ldb, ldc, 1, 0, 0, 0);
    };

    // ---- phase 3: self-attention ----
    u16* wqkv1t = (u16*)wpool;                       // [3072,1024] stacked
    u16* wo1t   = (u16*)(wpool) + 3L*1024*1024;
    {
        P6 pp{};
        pp.s[0]=(const float*)d_in[5]; pp.d[0]=wqkv1t;
        pp.s[1]=(const float*)d_in[6]; pp.d[1]=wqkv1t + 1L*1024*1024;
        pp.s[2]=(const float*)d_in[7]; pp.d[2]=wqkv1t + 2L*1024*1024;
        pp.s[3]=(const float*)d_in[8]; pp.d[3]=wo1t;
        transpose_cast_batch<<<dim3(32, 32, 4), blk, 0, stream>>>(pp, 1024, 1024);
    }
    cast(x, bufA, 4096L*1024);
    g_n(bufA, wqkv1t, qkv1, 4096, 3072, 1024, 1024, 1024, 3072);
    flash_attn_kernel<true><<<dim3(16, 16, 4), blk, 0, stream>>>(
        qkv1, qkv1 + 1024, qkv1 + 2048, nullptr, bufA, 3072, 3072, 3072);
    g_f(bufA, wo1t, x2a, 4096, 1024, 1024, 1024, 1024, 1024);
    ln1_kernel<<<dim3(4096), blk, 0, stream>>>(x, x2a, intent, g1, be1, yibf);

    // ---- phase 4: selective hierarchical attention ----
    u16* wq3t = (u16*)wpool;
    {
        P6 pp{};
        pp.s[0]=(const float*)d_in[9];  pp.d[0]=wq3t;
        pp.s[1]=(const float*)d_in[10]; pp.d[1]=wq3t + 1L*1024*1280;
        pp.s[2]=(const float*)d_in[15]; pp.d[2]=wq3t + 2L*1024*1280;
        transpose_cast_batch<<<dim3(32, 40, 3), blk, 0, stream>>>(pp, 1280, 1024);
    }
    g_n(yibf, wq3t, buf3, 4096, 3072, 1280, 1280, 1280, 3072);   // qs|qt|q2
    u16* wkst = (u16*)wpool;
    u16* wkv  = (u16*)(wpool) + 1L*1024*1024;
    {
        P6 pp{};
        pp.s[0]=(const float*)d_in[11]; pp.d[0]=wkst;
        pp.s[1]=(const float*)d_in[12]; pp.d[1]=wkv;
        pp.s[2]=(const float*)d_in[13]; pp.d[2]=wkv + 1L*1024*1024;
        transpose_cast_batch<<<dim3(32, 32, 3), blk, 0, stream>>>(pp, 1024, 1024);
    }
    cast(sfeat, sfbf, 64L*1024);
    cast(stat_e, sebf, 16384L*1024);
    g_n(sfbf, wkst, ksbf, 64, 1024, 1024, 1024, 1024, 1024);
    g_n(sebf, wkv, ktvv, 16384, 2048, 1024, 1024, 1024, 2048);   // kt|vv
    ssc_kernel<<<dim3(1024, 4), blk, 0, stream>>>(buf3, ksbf, svl, sscf, 3072);
    for (int hh = 0; hh < 2; hh++) {
        long t0 = hh * 512;
        gemm_bt<float,false,false><<<dim3(2, 4, 64), blk, 0, stream>>>(
            buf3 + 1024 + t0*3072, ktvv, tsch, nullptr, 512, 256, 1024,
            3072, 2048, 256, 16, (long)T_N*3072, 256L*2048, 512L*256);
        select_combine_kernel<<<dim3(512, 4), blk, 0, stream>>>(
            sscf, tsch, ktvv + 1024, bufA, (int)t0, 2048);
    }
    u16* wost = (u16*)wpool;
    u16* wkv2 = (u16*)(wpool) + 1L*1024*1024;
    u16* wo2t = (u16*)(wpool) + 3L*1024*1024;
    {
        P6 pp{};
        pp.s[0]=(const float*)d_in[14]; pp.d[0]=wost;
        pp.s[1]=(const float*)d_in[16]; pp.d[1]=wkv2;
        pp.s[2]=(const float*)d_in[17]; pp.d[2]=wkv2 + 1L*1024*1024;
        pp.s[3]=(const float*)d_in[18]; pp.d[3]=wo2t;
        transpose_cast_batch<<<dim3(32, 32, 4), blk, 0, stream>>>(pp, 1024, 1024);
    }
    g_f(bufA, wost, y2sf, 4096, 1024, 1024, 1024, 1024, 1024);

    // ---- phase 5: exemplar cross-attention ----
    cast(exem, exbf, 4096L*1024);
    g_n(exbf, wkv2, kv2, 4096, 2048, 1024, 1024, 1024, 2048);    // k2|v2
    flash_attn_kernel<false><<<dim3(16, 16, 4), blk, 0, stream>>>(
        buf3 + 2048, kv2, kv2 + 1024, evl, bufA, 3072, 2048, 2048);
    g_f(bufA, wo2t, y2ef, 4096, 1024, 1024, 1024, 1024, 1024);

    // ---- phase 6: gate + LN2 ----
    gate_ln2_kernel<<<dim3(4096), blk, 0, stream>>>(yibf, y2sf, y2ef, Wg, g2, be2, zf, zbf);

    // ---- phase 7: FFN ----
    {
        P6 pp{}; pp.s[0] = (const float*)d_in[20]; pp.d[0] = w1t;
        transpose_cast_batch<<<dim3(128, 32, 1), blk, 0, stream>>>(pp, 1024, 4096);
    }
    {
        P6 pp{}; pp.s[0] = (const float*)d_in[22]; pp.d[0] = w2t;
        transpose_cast_batch<<<dim3(32, 128, 1), blk, 0, stream>>>(pp, 4096, 1024);
    }
    gemm_bt<u16,true,true><<<dim3(32, 32, 1), blk, 0, stream>>>(
        zbf, w1t, hid, b1, 4096, 4096, 1024, 1024, 1024, 4096, 1, 0, 0, 0);
    // FFN2 split-K x2 in one dispatch (z picks K-half): p[z] = hid[:,z*2048:] @ w2t[:,z*2048:]^T
    gemm_bt<float,false,false><<<dim3(8, 32, 2), blk, 0, stream>>>(
        hid, w2t, p0f, nullptr, 4096, 1024, 2048, 4096, 4096, 1024,
        1, 2048, 2048, 4096L*1024);

    // ---- phase 8: final LN (fuses p0+p1+b2) ----
    ln3_kernel<<<dim3(4096), blk, 0, stream>>>(zf, p0f, p0f + 4096L*1024, b2, g3, be3, outp);
}